// Round 12
// baseline (175.913 us; speedup 1.0000x reference)
//
#include <hip/hip_runtime.h>

#define SLEN 2048
#define PATCH 16
#define ND 4
#define NW 2033          // windows per dilation = S - P + 1
#define NCAND 8132       // ND * NW
#define NROWS 256        // B * C
#define NCH 8
#define ROWPAD 8192      // padded per-row stride for cmb/sel

// ws layout (bytes):
//   sel   : u16   [NROWS*ROWPAD]  @ 0         ( 4 MB)
//   convf : float [NROWS*ND*SLEN] @ 16777216  ( 8 MB)
//   cmb   : uchar [NROWS*ROWPAD]  @ 25165824  ( 2 MB)

#define CDX(x) ((x) + ((x) >> 4))   // f64 LDS pad (cm-phase lane stride 8 f64)

typedef float fv4 __attribute__((ext_vector_type(4)));   // clang vector: NT-store ok

// Fused conv + can_merge per (row, dilation) block. conv f64 lives in LDS;
// convf f32 to global for k_out; cm bytes to cmb. No convd in global.
__global__ __launch_bounds__(256) void k_convcm(
    const float* __restrict__ seasonal,
    const float* __restrict__ conv_w,
    const float* __restrict__ conv_b,
    float* __restrict__ convf,
    unsigned char* __restrict__ cmb)
{
    const int bid = blockIdx.x;
    const int row = bid >> 2;     // 0..255 (= b*8 + c)
    const int d   = bid & 3;
    const int dil = 1 << d;       // DILATIONS = (1,2,4,8)
    const int b = row >> 3, c = row & 7;
    const int tid = threadIdx.x;

    __shared__ float xs[SLEN];                 //  8 KB
    __shared__ double cd[CDX(SLEN-1)+1];       // 17.5 KB padded f64 conv

    #pragma unroll
    for (int j = 0; j < SLEN/256; ++j) {
        int s = tid + j*256;
        xs[s] = seasonal[(size_t)(b*SLEN + s)*NCH + c];
    }
    double w[PATCH];
    #pragma unroll
    for (int k = 0; k < PATCH; ++k) w[k] = (double)conv_w[d*PATCH + k];
    const double bias = (double)conv_b[d];
    __syncthreads();

    const size_t obase = (size_t)row*8192 + d*SLEN;
    #pragma unroll
    for (int j = 0; j < SLEN/256; ++j) {
        int t = tid + j*256;
        double acc = 0.0;
        #pragma unroll
        for (int k = 0; k < PATCH; ++k) {
            int idx = t - (PATCH-1-k)*dil;     // only left pad clips
            if (idx >= 0) acc += w[k] * (double)xs[idx];
        }
        acc += bias;
        cd[CDX(t)] = acc;
        convf[obase + t] = (float)acc;
    }
    __syncthreads();

    unsigned char* crow = cmb + (size_t)row*ROWPAD + d*NW;
    if (tid < 254) {               // sliding-window stats, source = LDS
        const int w0 = tid*8;      // pairs w0..w0+7 (max 2031)
        double W1=0.0, W2=0.0, Wk=0.0;
        #pragma unroll
        for (int k = 0; k < 16; ++k) {
            double v = cd[CDX(w0+k)];
            W1 += v; W2 = fma(v,v,W2); Wk = fma((double)k,v,Wk);
        }
        unsigned char bits[8];
        #pragma unroll
        for (int j = 0; j < 8; ++j) {
            double v0 = cd[CDX(w0+j)], v16 = cd[CDX(w0+j+16)];
            double nW1 = W1 + (v16 - v0);
            double nW2 = W2 + (v16*v16 - v0*v0);
            double nWk = Wk - W1 + v0 + 15.0*v16;
            double S1  = W1 + nW1;
            double S2  = W2 + nW2;
            double Sxy = (Wk - 15.5*W1) + (nWk + 0.5*nW1);
            double syy = S2 - S1*S1*(1.0/32.0);
            bits[j] = (unsigned char)((Sxy*Sxy >= 1364.0*syy) && (syy > 0.0));
            W1 = nW1; W2 = nW2; Wk = nWk;
        }
        #pragma unroll
        for (int j = 0; j < 8; ++j) crow[w0+j] = bits[j];
    } else if (tid == 255 && d < 3) {
        // boundary pair (d,2032)-(d+1,0): recompute conv_{d+1}[0..15] f64 from xs
        const int dil2 = dil << 1;
        double w2[PATCH];
        #pragma unroll
        for (int k = 0; k < PATCH; ++k) w2[k] = (double)conv_w[(d+1)*PATCH + k];
        const double bias2 = (double)conv_b[d+1];
        double aW1=0,aW2=0,aWk=0, bW1=0,bW2=0,bWk=0;
        #pragma unroll
        for (int k = 0; k < 16; ++k) {
            double va = cd[CDX(2032+k)];
            double acc = 0.0;
            #pragma unroll
            for (int q = 0; q < PATCH; ++q) {
                int idx = k - (PATCH-1-q)*dil2;
                if (idx >= 0) acc += w2[q] * (double)xs[idx];
            }
            double vb = acc + bias2;
            aW1 += va; aW2 = fma(va,va,aW2); aWk = fma((double)k,va,aWk);
            bW1 += vb; bW2 = fma(vb,vb,bW2); bWk = fma((double)k,vb,bWk);
        }
        double S1  = aW1 + bW1;
        double S2  = aW2 + bW2;
        double Sxy = (aWk - 15.5*aW1) + (bWk + 0.5*bW1);
        double syy = S2 - S1*S1*(1.0/32.0);
        crow[2032] = (unsigned char)((Sxy*Sxy >= 1364.0*syy) && (syy > 0.0));
    }
}

// scan + stable compaction per row; writes u16 sel (+ 0xFFFF sentinel to NCAND)
__global__ __launch_bounds__(256) void k_pack(
    const unsigned char* __restrict__ cmb,
    unsigned short* __restrict__ sel)
{
    const int row = blockIdx.x;
    const int tid = threadIdx.x;
    __shared__ unsigned char c0out[256];
    __shared__ int pmax[256];
    __shared__ unsigned sums[256];

    const unsigned* cmw = (const unsigned*)(cmb + (size_t)row*ROWPAD);
    unsigned cmbits = 0;
    #pragma unroll
    for (int q = 0; q < 8; ++q) {
        unsigned wrd = cmw[tid*8 + q];
        #pragma unroll
        for (int bb = 0; bb < 4; ++bb) {
            int p = tid*32 + q*4 + bb;
            unsigned bit = ((wrd >> (8*bb)) & 0xffu) ? 1u : 0u;
            if (p >= NCAND-1) bit = 0;           // pad-false + garbage-tail mask
            cmbits |= bit << (q*4 + bb);
        }
    }

    // chunk function: out = parity of ones-run at top of word; all-ones = identity
    unsigned inv = ~cmbits;
    unsigned T = (inv == 0u) ? 32u : (unsigned)__clz(inv);
    c0out[tid] = (unsigned char)(T & 1u);
    pmax[tid]  = (inv == 0u) ? -1 : tid;
    __syncthreads();
    for (int off = 1; off < 256; off <<= 1) {    // inclusive prefix-max
        int v = (tid >= off) ? pmax[tid-off] : -1;
        __syncthreads();
        if (v > pmax[tid]) pmax[tid] = v;
        __syncthreads();
    }
    unsigned carry = 0;
    if (tid > 0) { int m = pmax[tid-1]; if (m >= 0) carry = c0out[m]; }

    unsigned cons = carry;
    unsigned validb = 0, mergeb = 0;
    int cnt = 0;
    const int base = tid*32;
    int nelem = NCAND - base; if (nelem > 32) nelem = 32; if (nelem < 0) nelem = 0;
    for (int w = 0; w < nelem; ++w) {
        unsigned bit = (cmbits >> w) & 1u;
        unsigned val = cons ^ 1u;
        unsigned mrg = bit & val;
        validb |= val << w;
        mergeb |= mrg << w;
        cnt += (int)val;
        cons = mrg;
    }

    sums[tid] = (unsigned)cnt;
    __syncthreads();
    for (int off = 1; off < 256; off <<= 1) {
        unsigned v = (tid >= off) ? sums[tid-off] : 0u;
        __syncthreads();
        sums[tid] += v;
        __syncthreads();
    }
    unsigned r = sums[tid] - (unsigned)cnt;
    unsigned total = sums[255];
    unsigned short* selrow = sel + (size_t)row*ROWPAD;
    for (int w = 0; w < nelem; ++w) {
        if ((validb >> w) & 1u)
            selrow[r++] = (unsigned short)((((base + w) << 1) | (int)((mergeb >> w) & 1u)));
    }
    for (int idx = (int)total + tid; idx < NCAND; idx += 256)
        selrow[idx] = 0xFFFFu;   // sentinel; k_out reads only n < NCAND
}

// Block = (b, chunk of 32 n). Valid i advances by 1 or 2 per slot and a chunk
// crosses <=1 dilation boundary, so all reads lie in [a0, a0+94] where a0 is
// the FIRST valid slot's linear addr (a(i)=i+15d monotone; packing is a valid
// prefix + sentinel tail). Fixed 96-float span load -> LDS gather -> tile ->
// nontemporal streaming dwordx4 out.
__global__ __launch_bounds__(256) void k_out(
    const float* __restrict__ convf,
    const unsigned short* __restrict__ sel,
    float* __restrict__ out)
{
    __shared__ float gbuf[8*100];                // 96-float spans, stride 100
    __shared__ int   base_s[8];                  // a0 per row (-1 if chunk empty)
    __shared__ float tile[32*132];               // output staging, +4-word row pad

    const int t = threadIdx.x;
    const int c = t & 7;
    const int s = t >> 3;                        // 0..31
    const unsigned bq = blockIdx.x;
    const unsigned b  = bq / 255u;               // 32 batches x 255 chunks
    const unsigned m  = bq - b*255u;
    const int n0 = (int)m*32;
    const int ns = (NCAND - n0 < 32) ? (NCAND - n0) : 32;   // 32 or 4 (tail)
    const unsigned row = b*NCH + (unsigned)c;

    // own sel entry (issued before the barrier; overlaps base discovery)
    int e = -1;
    if (s < ns) {
        unsigned short e16 = sel[(size_t)row*ROWPAD + (n0 + s)];
        e = (e16 == 0xFFFFu) ? -1 : (int)e16;
    }
    if (t < 8) {
        unsigned short e0 = sel[(size_t)(b*NCH + t)*ROWPAD + n0];
        int a0 = -1;
        if (e0 != 0xFFFFu) {
            int i0 = ((int)e0) >> 1;
            int d0 = (i0 >= 3*NW) ? 3 : (i0 >= 2*NW) ? 2 : (i0 >= NW) ? 1 : 0;
            a0 = i0 + 15*d0;
        }
        base_s[t] = a0;
    }
    __syncthreads();

    {   // cooperative fixed-span load: 32 lanes per row, 8 rows
        const int r = t >> 5, j = t & 31;
        const int a0 = base_s[r];
        if (a0 >= 0) {
            const float* src = convf + (size_t)(b*NCH + r)*8192;
            #pragma unroll
            for (int q = 0; q < 3; ++q) {
                int o = j + q*32;
                int a = a0 + o;
                gbuf[r*100 + o] = (a < 8192) ? src[a] : 0.0f;  // clamp: row end
            }
        }
    }
    __syncthreads();

    float vals[16];
    if (e < 0) {
        #pragma unroll
        for (int k = 0; k < 16; ++k) vals[k] = 0.0f;
    } else {
        const int i  = e >> 1;
        const int d  = (i >= 3*NW) ? 3 : (i >= 2*NW) ? 2 : (i >= NW) ? 1 : 0;
        const int ai = i + 15*d;
        const int a0 = base_s[c];
        const float* f = gbuf + c*100 + (ai - a0);
        if (e & 1) {
            const int i2 = i + 1;                // i=NCAND-1 merge masked in k_pack
            const int d2 = (i2 >= 3*NW) ? 3 : (i2 >= 2*NW) ? 2 : (i2 >= NW) ? 1 : 0;
            const float* g = gbuf + c*100 + (i2 + 15*d2 - a0);
            #pragma unroll
            for (int k = 0; k < 16; ++k) vals[k] = 0.5f*(f[k] + g[k]);
        } else {
            #pragma unroll
            for (int k = 0; k < 16; ++k) vals[k] = f[k];
        }
    }
    if (s < ns) {
        float* tr = tile + s*132 + c;
        #pragma unroll
        for (int k = 0; k < 16; ++k) tr[k*8] = vals[k];
    }
    __syncthreads();

    const size_t obase = ((size_t)b*NCAND + n0)*128;   // contiguous block range
    const int nw = ns*128;
    #pragma unroll
    for (int m2 = 0; m2 < 4; ++m2) {
        int L = (t + m2*256)*4;
        if (L < nw) {
            int s2 = L >> 7, j = L & 127;
            fv4 v = *(const fv4*)&tile[s2*132 + j];
            __builtin_nontemporal_store(v, (fv4*)&out[obase + L]);
        }
    }
}

extern "C" void kernel_launch(void* const* d_in, const int* in_sizes, int n_in,
                              void* d_out, int out_size, void* d_ws, size_t ws_size,
                              hipStream_t stream) {
    const float* seasonal = (const float*)d_in[0];
    const float* conv_w   = (const float*)d_in[1];
    const float* conv_b   = (const float*)d_in[2];
    float* out = (float*)d_out;

    char* ws = (char*)d_ws;
    unsigned short* sel   = (unsigned short*)(ws);
    float*          convf = (float*)(ws + 16777216);
    unsigned char*  cmb   = (unsigned char*)(ws + 25165824);

    hipLaunchKernelGGL(k_convcm, dim3(NROWS*ND), dim3(256), 0, stream,
                       seasonal, conv_w, conv_b, convf, cmb);
    hipLaunchKernelGGL(k_pack,   dim3(NROWS), dim3(256), 0, stream,
                       cmb, sel);
    hipLaunchKernelGGL(k_out,    dim3(32*255), dim3(256), 0, stream,
                       convf, sel, out);
}

// Round 13
// 169.178 us; speedup vs baseline: 1.0398x; 1.0398x over previous
//
#include <hip/hip_runtime.h>

#define SLEN 2048
#define PATCH 16
#define ND 4
#define NW 2033          // windows per dilation = S - P + 1
#define NCAND 8132       // ND * NW
#define NROWS 256        // B * C
#define NCH 8
#define ROWPAD 8192      // padded per-row stride for cmb/sel

// ws layout (bytes):
//   sel   : u16   [NROWS*ROWPAD]  @ 0         ( 4 MB)
//   convf : float [NROWS*ND*SLEN] @ 16777216  ( 8 MB)
//   cmb   : uchar [NROWS*ROWPAD]  @ 25165824  ( 2 MB)

#define CDX(x) ((x) + ((x) >> 4))   // f64 LDS pad (cm-phase lane stride 8 f64)

// Fused conv + can_merge per (row, dilation) block. conv f64 lives in LDS;
// convf f32 to global for k_out; cm bytes to cmb. No convd in global.
__global__ __launch_bounds__(256) void k_convcm(
    const float* __restrict__ seasonal,
    const float* __restrict__ conv_w,
    const float* __restrict__ conv_b,
    float* __restrict__ convf,
    unsigned char* __restrict__ cmb)
{
    const int bid = blockIdx.x;
    const int row = bid >> 2;     // 0..255 (= b*8 + c)
    const int d   = bid & 3;
    const int dil = 1 << d;       // DILATIONS = (1,2,4,8)
    const int b = row >> 3, c = row & 7;
    const int tid = threadIdx.x;

    __shared__ float xs[SLEN];                 //  8 KB
    __shared__ double cd[CDX(SLEN-1)+1];       // 17.5 KB padded f64 conv

    #pragma unroll
    for (int j = 0; j < SLEN/256; ++j) {
        int s = tid + j*256;
        xs[s] = seasonal[(size_t)(b*SLEN + s)*NCH + c];
    }
    double w[PATCH];
    #pragma unroll
    for (int k = 0; k < PATCH; ++k) w[k] = (double)conv_w[d*PATCH + k];
    const double bias = (double)conv_b[d];
    __syncthreads();

    const size_t obase = (size_t)row*8192 + d*SLEN;
    #pragma unroll
    for (int j = 0; j < SLEN/256; ++j) {
        int t = tid + j*256;
        double acc = 0.0;
        #pragma unroll
        for (int k = 0; k < PATCH; ++k) {
            int idx = t - (PATCH-1-k)*dil;     // only left pad clips
            if (idx >= 0) acc += w[k] * (double)xs[idx];
        }
        acc += bias;
        cd[CDX(t)] = acc;
        convf[obase + t] = (float)acc;
    }
    __syncthreads();

    unsigned char* crow = cmb + (size_t)row*ROWPAD + d*NW;
    if (tid < 254) {               // sliding-window stats, source = LDS
        const int w0 = tid*8;      // pairs w0..w0+7 (max 2031)
        double W1=0.0, W2=0.0, Wk=0.0;
        #pragma unroll
        for (int k = 0; k < 16; ++k) {
            double v = cd[CDX(w0+k)];
            W1 += v; W2 = fma(v,v,W2); Wk = fma((double)k,v,Wk);
        }
        unsigned char bits[8];
        #pragma unroll
        for (int j = 0; j < 8; ++j) {
            double v0 = cd[CDX(w0+j)], v16 = cd[CDX(w0+j+16)];
            double nW1 = W1 + (v16 - v0);
            double nW2 = W2 + (v16*v16 - v0*v0);
            double nWk = Wk - W1 + v0 + 15.0*v16;
            double S1  = W1 + nW1;
            double S2  = W2 + nW2;
            double Sxy = (Wk - 15.5*W1) + (nWk + 0.5*nW1);
            double syy = S2 - S1*S1*(1.0/32.0);
            bits[j] = (unsigned char)((Sxy*Sxy >= 1364.0*syy) && (syy > 0.0));
            W1 = nW1; W2 = nW2; Wk = nWk;
        }
        #pragma unroll
        for (int j = 0; j < 8; ++j) crow[w0+j] = bits[j];
    } else if (tid == 255 && d < 3) {
        // boundary pair (d,2032)-(d+1,0): recompute conv_{d+1}[0..15] f64 from xs
        const int dil2 = dil << 1;
        double w2[PATCH];
        #pragma unroll
        for (int k = 0; k < PATCH; ++k) w2[k] = (double)conv_w[(d+1)*PATCH + k];
        const double bias2 = (double)conv_b[d+1];
        double aW1=0,aW2=0,aWk=0, bW1=0,bW2=0,bWk=0;
        #pragma unroll
        for (int k = 0; k < 16; ++k) {
            double va = cd[CDX(2032+k)];
            double acc = 0.0;
            #pragma unroll
            for (int q = 0; q < PATCH; ++q) {
                int idx = k - (PATCH-1-q)*dil2;
                if (idx >= 0) acc += w2[q] * (double)xs[idx];
            }
            double vb = acc + bias2;
            aW1 += va; aW2 = fma(va,va,aW2); aWk = fma((double)k,va,aWk);
            bW1 += vb; bW2 = fma(vb,vb,bW2); bWk = fma((double)k,vb,bWk);
        }
        double S1  = aW1 + bW1;
        double S2  = aW2 + bW2;
        double Sxy = (aWk - 15.5*aW1) + (bWk + 0.5*bW1);
        double syy = S2 - S1*S1*(1.0/32.0);
        crow[2032] = (unsigned char)((Sxy*Sxy >= 1364.0*syy) && (syy > 0.0));
    }
}

// scan + stable compaction per row; writes u16 sel (+ 0xFFFF sentinel to NCAND)
__global__ __launch_bounds__(256) void k_pack(
    const unsigned char* __restrict__ cmb,
    unsigned short* __restrict__ sel)
{
    const int row = blockIdx.x;
    const int tid = threadIdx.x;
    __shared__ unsigned char c0out[256];
    __shared__ int pmax[256];
    __shared__ unsigned sums[256];

    const unsigned* cmw = (const unsigned*)(cmb + (size_t)row*ROWPAD);
    unsigned cmbits = 0;
    #pragma unroll
    for (int q = 0; q < 8; ++q) {
        unsigned wrd = cmw[tid*8 + q];
        #pragma unroll
        for (int bb = 0; bb < 4; ++bb) {
            int p = tid*32 + q*4 + bb;
            unsigned bit = ((wrd >> (8*bb)) & 0xffu) ? 1u : 0u;
            if (p >= NCAND-1) bit = 0;           // pad-false + garbage-tail mask
            cmbits |= bit << (q*4 + bb);
        }
    }

    // chunk function: out = parity of ones-run at top of word; all-ones = identity
    unsigned inv = ~cmbits;
    unsigned T = (inv == 0u) ? 32u : (unsigned)__clz(inv);
    c0out[tid] = (unsigned char)(T & 1u);
    pmax[tid]  = (inv == 0u) ? -1 : tid;
    __syncthreads();
    for (int off = 1; off < 256; off <<= 1) {    // inclusive prefix-max
        int v = (tid >= off) ? pmax[tid-off] : -1;
        __syncthreads();
        if (v > pmax[tid]) pmax[tid] = v;
        __syncthreads();
    }
    unsigned carry = 0;
    if (tid > 0) { int m = pmax[tid-1]; if (m >= 0) carry = c0out[m]; }

    unsigned cons = carry;
    unsigned validb = 0, mergeb = 0;
    int cnt = 0;
    const int base = tid*32;
    int nelem = NCAND - base; if (nelem > 32) nelem = 32; if (nelem < 0) nelem = 0;
    for (int w = 0; w < nelem; ++w) {
        unsigned bit = (cmbits >> w) & 1u;
        unsigned val = cons ^ 1u;
        unsigned mrg = bit & val;
        validb |= val << w;
        mergeb |= mrg << w;
        cnt += (int)val;
        cons = mrg;
    }

    sums[tid] = (unsigned)cnt;
    __syncthreads();
    for (int off = 1; off < 256; off <<= 1) {
        unsigned v = (tid >= off) ? sums[tid-off] : 0u;
        __syncthreads();
        sums[tid] += v;
        __syncthreads();
    }
    unsigned r = sums[tid] - (unsigned)cnt;
    unsigned total = sums[255];
    unsigned short* selrow = sel + (size_t)row*ROWPAD;
    for (int w = 0; w < nelem; ++w) {
        if ((validb >> w) & 1u)
            selrow[r++] = (unsigned short)((((base + w) << 1) | (int)((mergeb >> w) & 1u)));
    }
    for (int idx = (int)total + tid; idx < NCAND; idx += 256)
        selrow[idx] = 0xFFFFu;   // sentinel; k_out reads only n < NCAND
}

// Block = (b, chunk of 32 n). Valid i advances by 1..2 per n, so 32 n of one
// row touch a contiguous <=95-float span of convf (a(i)=i+15d monotone).
// Cooperative span load -> LDS gather -> tile -> streaming dwordx4 out.
__global__ __launch_bounds__(256) void k_out(
    const float* __restrict__ convf,
    const unsigned short* __restrict__ sel,
    float* __restrict__ out)
{
    __shared__ float gbuf[8*132];                // per-row conv spans (<=95 used)
    __shared__ int   amin_s[8], amax_s[8];
    __shared__ float tile[32*132];               // output staging, +4-word row pad

    const int t = threadIdx.x;
    const int c = t & 7;
    const int s = t >> 3;                        // 0..31
    const unsigned bq = blockIdx.x;
    const unsigned b  = bq / 255u;               // 32 batches x 255 chunks
    const unsigned m  = bq - b*255u;
    const int n0 = (int)m*32;
    const int ns = (NCAND - n0 < 32) ? (NCAND - n0) : 32;   // 32 or 4 (tail)
    const unsigned row = b*NCH + (unsigned)c;

    if (t < 8) { amin_s[t] = 0x7fffffff; amax_s[t] = -1; }
    __syncthreads();

    int e = -1, ai = 0, ai2 = 0;
    if (s < ns) {
        unsigned short e16 = sel[(size_t)row*ROWPAD + (n0 + s)];
        e = (e16 == 0xFFFFu) ? -1 : (int)e16;
        if (e >= 0) {
            const int i  = e >> 1;
            const int d  = (i >= 3*NW) ? 3 : (i >= 2*NW) ? 2 : (i >= NW) ? 1 : 0;
            ai = i + 15*d;                       // linear addr in row (d*2048 + i-d*NW)
            int ae;
            if (e & 1) {
                const int i2 = i + 1;            // i=NCAND-1 merge masked in k_pack
                const int d2 = (i2 >= 3*NW) ? 3 : (i2 >= 2*NW) ? 2 : (i2 >= NW) ? 1 : 0;
                ai2 = i2 + 15*d2;
                ae = ai2 + 16;
            } else {
                ai2 = ai;
                ae = ai + 16;
            }
            atomicMin(&amin_s[c], ai);
            atomicMax(&amax_s[c], ae);
        }
    }
    __syncthreads();

    {   // cooperative contiguous span load: 32 lanes per row, 8 rows
        const int r = t >> 5, j = t & 31;
        const int lo = amin_s[r], hi = amax_s[r];
        if (lo <= hi) {
            const float* src = convf + (size_t)(b*NCH + r)*8192;
            for (int o = j; o <= hi - lo; o += 32)
                gbuf[r*132 + o] = src[lo + o];
        }
    }
    __syncthreads();

    float vals[16];
    if (e < 0) {
        #pragma unroll
        for (int k = 0; k < 16; ++k) vals[k] = 0.0f;
    } else {
        const float* f = gbuf + c*132 + (ai  - amin_s[c]);
        const float* g = gbuf + c*132 + (ai2 - amin_s[c]);
        if (e & 1) {
            #pragma unroll
            for (int k = 0; k < 16; ++k) vals[k] = 0.5f*(f[k] + g[k]);
        } else {
            #pragma unroll
            for (int k = 0; k < 16; ++k) vals[k] = f[k];
        }
    }
    if (s < ns) {
        float* tr = tile + s*132 + c;
        #pragma unroll
        for (int k = 0; k < 16; ++k) tr[k*8] = vals[k];
    }
    __syncthreads();

    const size_t obase = ((size_t)b*NCAND + n0)*128;   // contiguous block range
    const int nw = ns*128;
    #pragma unroll
    for (int m2 = 0; m2 < 4; ++m2) {
        int L = (t + m2*256)*4;
        if (L < nw) {
            int s2 = L >> 7, j = L & 127;
            float4 v = *(const float4*)&tile[s2*132 + j];
            *(float4*)&out[obase + L] = v;
        }
    }
}

extern "C" void kernel_launch(void* const* d_in, const int* in_sizes, int n_in,
                              void* d_out, int out_size, void* d_ws, size_t ws_size,
                              hipStream_t stream) {
    const float* seasonal = (const float*)d_in[0];
    const float* conv_w   = (const float*)d_in[1];
    const float* conv_b   = (const float*)d_in[2];
    float* out = (float*)d_out;

    char* ws = (char*)d_ws;
    unsigned short* sel   = (unsigned short*)(ws);
    float*          convf = (float*)(ws + 16777216);
    unsigned char*  cmb   = (unsigned char*)(ws + 25165824);

    hipLaunchKernelGGL(k_convcm, dim3(NROWS*ND), dim3(256), 0, stream,
                       seasonal, conv_w, conv_b, convf, cmb);
    hipLaunchKernelGGL(k_pack,   dim3(NROWS), dim3(256), 0, stream,
                       cmb, sel);
    hipLaunchKernelGGL(k_out,    dim3(32*255), dim3(256), 0, stream,
                       convf, sel, out);
}